// Round 10
// baseline (200.774 us; speedup 1.0000x reference)
//
#include <hip/hip_runtime.h>
#include <cstdint>
#include <cstddef>

#define L_SEQ  2048
#define DMODEL 1024
#define NHEADS 16
#define HDIM   64
#define NQKV   3072

typedef float f32x4 __attribute__((ext_vector_type(4)));
typedef short s16x8 __attribute__((ext_vector_type(8)));

static __device__ __forceinline__ unsigned short f2bf(float f) {
  unsigned u = __float_as_uint(f);
  return (unsigned short)((u + 0x7fffu + ((u >> 16) & 1u)) >> 16);
}

// async global->LDS, 16B per lane; lds base wave-uniform, global per-lane
static __device__ __forceinline__ void gld_lds16(void* lds, const void* g) {
  __builtin_amdgcn_global_load_lds(
      (const __attribute__((address_space(1))) void*)g,
      (__attribute__((address_space(3))) void*)lds, 16, 0, 0);
}

// ---------------------------------------------------------------- convert
__global__ __launch_bounds__(256) void cvt_kernel(
    const float* __restrict__ x, const float* __restrict__ wqkv,
    const float* __restrict__ wout,
    unsigned short* __restrict__ xb, unsigned short* __restrict__ wqkvb,
    unsigned short* __restrict__ woutb) {
  const int NX = L_SEQ * DMODEL / 4;
  const int NW1 = NQKV * DMODEL / 4;
  const int NW2 = DMODEL * DMODEL / 4;
  const int tot = NX + NW1 + NW2;
  for (int i = blockIdx.x * blockDim.x + threadIdx.x; i < tot;
       i += gridDim.x * blockDim.x) {
    const float4* s;
    unsigned short* d;
    int j;
    if (i < NX) { s = (const float4*)x; d = xb; j = i; }
    else if (i < NX + NW1) { s = (const float4*)wqkv; d = wqkvb; j = i - NX; }
    else { s = (const float4*)wout; d = woutb; j = i - NX - NW1; }
    float4 v = s[j];
    ushort4 o;
    o.x = f2bf(v.x); o.y = f2bf(v.y); o.z = f2bf(v.z); o.w = f2bf(v.w);
    *(ushort4*)(d + 4 * (size_t)j) = o;
  }
}

// ------------------------------------------------- shared 128x128 GEMM core
template <int KDIM>
static __device__ __forceinline__ void gemm_bt_core(
    const unsigned short* __restrict__ A, const unsigned short* __restrict__ Bt,
    unsigned short* As, unsigned short* Bs, int bm, int bn, f32x4 acc[4][4]) {
  const int tid = threadIdx.x;
  const int lane = tid & 63;
  const int wave = tid >> 6;
  const int g = lane >> 4;
  const int li = lane & 15;
  const int wm = (wave >> 1) * 64;
  const int wn = (wave & 1) * 64;
  const int arow = tid >> 2;
  const int acolb = (tid & 3) << 4;
  const char* gA = (const char*)A + (size_t)(bm * 128 + arow) * (KDIM * 2) + acolb;
  const char* gB = (const char*)Bt + (size_t)(bn * 128 + arow) * (KDIM * 2) + acolb;
  char* lA = (char*)As + wave * 1024;
  char* lB = (char*)Bs + wave * 1024;
  const size_t half = (size_t)64 * KDIM * 2;
  for (int kt = 0; kt < KDIM; kt += 32) {
    __syncthreads();
    gld_lds16(lA, gA + kt * 2);
    gld_lds16(lA + 4096, gA + half + kt * 2);
    gld_lds16(lB, gB + kt * 2);
    gld_lds16(lB + 4096, gB + half + kt * 2);
    __syncthreads();
    const s16x8* Av = (const s16x8*)As;
    const s16x8* Bv = (const s16x8*)Bs;
    s16x8 af[4], bfv[4];
#pragma unroll
    for (int mt = 0; mt < 4; ++mt) af[mt] = Av[(wm + mt * 16 + li) * 4 + g];
#pragma unroll
    for (int nt = 0; nt < 4; ++nt) bfv[nt] = Bv[(wn + nt * 16 + li) * 4 + g];
#pragma unroll
    for (int mt = 0; mt < 4; ++mt)
#pragma unroll
      for (int nt = 0; nt < 4; ++nt)
        acc[mt][nt] = __builtin_amdgcn_mfma_f32_16x16x32_bf16(
            af[mt], bfv[nt], acc[mt][nt], 0, 0, 0);
  }
}

// ------------------------------------------------------------- QKV GEMM
__global__ __launch_bounds__(256, 2) void gemm_qkv_k(
    const unsigned short* __restrict__ A, const unsigned short* __restrict__ Bt,
    const float* __restrict__ bqkv, unsigned short* __restrict__ Qb,
    unsigned short* __restrict__ Kb, unsigned short* __restrict__ Vt) {
  __shared__ alignas(16) unsigned short As[128 * 32], Bs[128 * 32];
  f32x4 acc[4][4] = {};
  gemm_bt_core<DMODEL>(A, Bt, As, Bs, blockIdx.x, blockIdx.y, acc);
  const int lane = threadIdx.x & 63, wave = threadIdx.x >> 6;
  const int g = lane >> 4, li = lane & 15;
  const int wm = (wave >> 1) * 64, wn = (wave & 1) * 64;
#pragma unroll
  for (int mt = 0; mt < 4; ++mt)
#pragma unroll
    for (int nt = 0; nt < 4; ++nt)
#pragma unroll
      for (int r = 0; r < 4; ++r) {
        int i = blockIdx.x * 128 + wm + mt * 16 + 4 * g + r;
        int n = blockIdx.y * 128 + wn + nt * 16 + li;
        float v = acc[mt][nt][r] + bqkv[n];
        int s = n >> 10;
        int h = (n >> 6) & 15;
        int d = n & 63;
        if (s == 0)      Qb[(((size_t)h * L_SEQ + i) << 6) + d] = f2bf(v * 0.125f);
        else if (s == 1) Kb[(((size_t)h * L_SEQ + i) << 6) + d] = f2bf(v);
        else             Vt[(size_t)(h * 64 + d) * L_SEQ + i] = f2bf(v);
      }
}

// ------------------------------------------------------------- attention
// 2048 blocks, head->XCD affinity: all 128 i-blocks of head h land on XCD
// h%8 (2 heads x 512KB = 1MB K+V per XCD L2 -> K load-to-use ~L2 latency).
// Otherwise identical to R9: 4 waves split the 256-col j-chunk; bias via
// 1KB-contiguous f32x4 register loads, prefetch depth 2, double-buffered
// swizzled LDS tile; issue order K -> V -> bias pinned by sched_barrier.
__global__ __launch_bounds__(256, 2) void attn_k(
    const unsigned short* __restrict__ Qb, const unsigned short* __restrict__ Kb,
    const unsigned short* __restrict__ Vt, const float* __restrict__ bias,
    const float* __restrict__ gate, unsigned short* __restrict__ AO) {
  __shared__ alignas(16) float blds[2][16][256];  // 32 KB bias double-buffer
  __shared__ alignas(16) char plds[4 * 2048];     // 8 KB P transpose
  __shared__ float dls[4][16];
  // head->XCD affinity mapping (dispatch round-robins bid over 8 XCDs)
  const int bid = blockIdx.x;
  const int slot = bid >> 3;                  // 0..255
  const int h = (bid & 7) + 8 * (slot >> 7);  // head h on XCD h%8
  const int i0 = (slot & 127) * 16;
  const int tid = threadIdx.x, lane = tid & 63, wave = tid >> 6;
  const int g = lane >> 4, li = lane & 15;
  char* myP = plds + wave * 2048;
  const s16x8* Qv = (const s16x8*)(Qb + (((size_t)h * L_SEQ + i0) << 6));
  const s16x8 qf0 = Qv[li * 8 + g];
  const s16x8 qf1 = Qv[li * 8 + 4 + g];
  const float gh = gate[h];
  const float* bh = bias + (size_t)h * L_SEQ * L_SEQ + (size_t)i0 * L_SEQ;
  const s16x8* Kall = (const s16x8*)(Kb + (((size_t)h * L_SEQ) << 6));
  const int srow = wave * 4;  // this wave stages bias rows srow..srow+3
  f32x4 accO[4] = {};
  f32x4 lpart = {0.f, 0.f, 0.f, 0.f};

  f32x4 rbA[4], rbB[4];
  // prologue: bias(0) -> rbA, bias(1) -> rbB (rbB stays in flight)
#pragma unroll
  for (int q = 0; q < 4; ++q)
    rbA[q] = *(const f32x4*)(bh + (size_t)(srow + q) * L_SEQ + 4 * lane);
#pragma unroll
  for (int q = 0; q < 4; ++q)
    rbB[q] = *(const f32x4*)(bh + (size_t)(srow + q) * L_SEQ + 256 + 4 * lane);
  __builtin_amdgcn_sched_barrier(0);
  // write bias(0) -> buf0 (swizzled); compiler waits only rbA (rbB younger)
#pragma unroll
  for (int q = 0; q < 4; ++q) {
    const int rr = srow + q;
    char* dst = (char*)&blds[0][rr][0] + ((unsigned)(lane * 16) ^ ((rr & 7) << 4));
    *(f32x4*)dst = rbA[q];
  }
#pragma unroll
  for (int q = 0; q < 4; ++q) rbA[q] = rbB[q];  // rbA = bias(1)
  asm volatile("s_waitcnt lgkmcnt(0)" ::: "memory");
  __builtin_amdgcn_s_barrier();

  for (int t = 0; t < 8; ++t) {
    const int jg = t * 256 + wave * 64;
    // --- issue K (8 ops), V (8 ops): L2-resident via XCD affinity
    s16x8 k0[4], k1[4];
#pragma unroll
    for (int nt = 0; nt < 4; ++nt) {
      k0[nt] = Kall[(jg + nt * 16 + li) * 8 + g];
      k1[nt] = Kall[(jg + nt * 16 + li) * 8 + 4 + g];
    }
    s16x8 v0[4], v1[4];
#pragma unroll
    for (int dt = 0; dt < 4; ++dt) {
      const unsigned short* vb = Vt + (size_t)(h * 64 + dt * 16 + li) * L_SEQ + jg;
      v0[dt] = *(const s16x8*)(vb + 8 * g);
      v1[dt] = *(const s16x8*)(vb + 32 + 8 * g);
    }
    __builtin_amdgcn_sched_barrier(0);
    // --- issue bias(t+2) last (youngest -> survives all implicit waits)
    if (t < 6) {
#pragma unroll
      for (int q = 0; q < 4; ++q)
        rbB[q] = *(const f32x4*)(bh + (size_t)(srow + q) * L_SEQ +
                                 (t + 2) * 256 + 4 * lane);
    }
    __builtin_amdgcn_sched_barrier(0);
    // --- QK^T (implicit wait for K leaves V+bias in flight)
    f32x4 s[4];
#pragma unroll
    for (int nt = 0; nt < 4; ++nt) {
      f32x4 z = {0.f, 0.f, 0.f, 0.f};
      z = __builtin_amdgcn_mfma_f32_16x16x32_bf16(qf0, k0[nt], z, 0, 0, 0);
      z = __builtin_amdgcn_mfma_f32_16x16x32_bf16(qf1, k1[nt], z, 0, 0, 0);
      s[nt] = z;
    }
    // --- exp from LDS buf[t&1] (swizzled read); P -> wave-private LDS
    const float* blr = &blds[t & 1][0][0];
#pragma unroll
    for (int nt = 0; nt < 4; ++nt)
#pragma unroll
      for (int r = 0; r < 4; ++r) {
        const int row = 4 * g + r;
        const char* src = (const char*)(blr + row * 256) +
                          ((unsigned)((wave * 64 + nt * 16 + li) * 4) ^
                           ((row & 7) << 4));
        float p = __expf(fmaf(gh, *(const float*)src, s[nt][r]));
        lpart[r] += p;
        unsigned b = (unsigned)(row * 128 + (nt * 16 + li) * 2) ^
                     (unsigned)((row & 7) << 4);
        *(unsigned short*)(myP + b) = f2bf(p);
      }
    asm volatile("s_waitcnt lgkmcnt(0)" ::: "memory");
    const unsigned b0 = ((unsigned)(li * 128 + 16 * g)) ^ (unsigned)((li & 7) << 4);
    const unsigned b1 = ((unsigned)(li * 128 + 64 + 16 * g)) ^ (unsigned)((li & 7) << 4);
    const s16x8 pa0 = *(const s16x8*)(myP + b0);
    const s16x8 pa1 = *(const s16x8*)(myP + b1);
    // --- PV (implicit wait for V leaves bias in flight)
#pragma unroll
    for (int dt = 0; dt < 4; ++dt) {
      accO[dt] = __builtin_amdgcn_mfma_f32_16x16x32_bf16(pa0, v0[dt], accO[dt], 0, 0, 0);
      accO[dt] = __builtin_amdgcn_mfma_f32_16x16x32_bf16(pa1, v1[dt], accO[dt], 0, 0, 0);
    }
    // --- stage bias(t+1) regs -> buf[(t+1)&1]; rotate rbA <- rbB
    if (t < 7) {
#pragma unroll
      for (int q = 0; q < 4; ++q) {
        const int rr = srow + q;
        char* dst = (char*)&blds[(t + 1) & 1][rr][0] +
                    ((unsigned)(lane * 16) ^ ((rr & 7) << 4));
        *(f32x4*)dst = rbA[q];
      }
#pragma unroll
      for (int q = 0; q < 4; ++q) rbA[q] = rbB[q];
    }
    asm volatile("s_waitcnt lgkmcnt(0)" ::: "memory");
    __builtin_amdgcn_s_barrier();  // raw: no vmcnt drain
  }
  // denom across the 16 lanes of each row group
  float lrow[4];
#pragma unroll
  for (int r = 0; r < 4; ++r) {
    float tl = lpart[r];
    tl += __shfl_xor(tl, 1);
    tl += __shfl_xor(tl, 2);
    tl += __shfl_xor(tl, 4);
    tl += __shfl_xor(tl, 8);
    lrow[r] = tl;
  }
  __syncthreads();
  float* accL = &blds[0][0][0];  // reuse: [4][16][64] f32 = 16KB
#pragma unroll
  for (int dt = 0; dt < 4; ++dt)
#pragma unroll
    for (int r = 0; r < 4; ++r)
      accL[(wave * 16 + 4 * g + r) * 64 + dt * 16 + li] = accO[dt][r];
  if (li == 0) {
#pragma unroll
    for (int r = 0; r < 4; ++r) dls[wave][4 * g + r] = lrow[r];
  }
  __syncthreads();
  {
    const int row = tid >> 4;
    const int c4 = (tid & 15) * 4;
    f32x4 sum = {0.f, 0.f, 0.f, 0.f};
    float ds = 0.f;
#pragma unroll
    for (int w = 0; w < 4; ++w) {
      sum += *(const f32x4*)&accL[(w * 16 + row) * 64 + c4];
      ds += dls[w][row];
    }
    const float inv = 1.0f / ds;
    ushort4 o;
    o.x = f2bf(sum[0] * inv);
    o.y = f2bf(sum[1] * inv);
    o.z = f2bf(sum[2] * inv);
    o.w = f2bf(sum[3] * inv);
    *(ushort4*)(AO + (size_t)(i0 + row) * DMODEL + h * 64 + c4) = o;
  }
}

// ------------------------------------------------------------- out proj
__global__ __launch_bounds__(256, 2) void gemm_out_k(
    const unsigned short* __restrict__ A, const unsigned short* __restrict__ Bt,
    const float* __restrict__ bout, float* __restrict__ out) {
  __shared__ alignas(16) unsigned short As[128 * 32], Bs[128 * 32];
  f32x4 acc[4][4] = {};
  gemm_bt_core<DMODEL>(A, Bt, As, Bs, blockIdx.x, blockIdx.y, acc);
  const int lane = threadIdx.x & 63, wave = threadIdx.x >> 6;
  const int g = lane >> 4, li = lane & 15;
  const int wm = (wave >> 1) * 64, wn = (wave & 1) * 64;
#pragma unroll
  for (int mt = 0; mt < 4; ++mt)
#pragma unroll
    for (int nt = 0; nt < 4; ++nt)
#pragma unroll
      for (int r = 0; r < 4; ++r) {
        int i = blockIdx.x * 128 + wm + mt * 16 + 4 * g + r;
        int n = blockIdx.y * 128 + wn + nt * 16 + li;
        out[(size_t)i * DMODEL + n] = acc[mt][nt][r] + bout[n];
      }
}

// ---------------------------------------------------------------- launch
extern "C" void kernel_launch(void* const* d_in, const int* in_sizes, int n_in,
                              void* d_out, int out_size, void* d_ws,
                              size_t ws_size, hipStream_t stream) {
  const float* x = (const float*)d_in[0];
  const float* pb = (const float*)d_in[1];
  const float* gate = (const float*)d_in[2];
  const float* wqkv = (const float*)d_in[3];
  const float* bqkv = (const float*)d_in[4];
  const float* wout = (const float*)d_in[5];
  const float* bout = (const float*)d_in[6];

  unsigned short* ws = (unsigned short*)d_ws;
  unsigned short* xb = ws;
  unsigned short* wqkvb = xb + (size_t)L_SEQ * DMODEL;
  unsigned short* woutb = wqkvb + (size_t)NQKV * DMODEL;
  unsigned short* Qb = woutb + (size_t)DMODEL * DMODEL;
  unsigned short* Kb = Qb + (size_t)NHEADS * L_SEQ * HDIM;
  unsigned short* Vt = Kb + (size_t)NHEADS * L_SEQ * HDIM;
  unsigned short* AO = Vt + (size_t)NHEADS * L_SEQ * HDIM;

  cvt_kernel<<<1024, 256, 0, stream>>>(x, wqkv, wout, xb, wqkvb, woutb);
  gemm_qkv_k<<<dim3(16, 24), 256, 0, stream>>>(xb, wqkvb, bqkv, Qb, Kb, Vt);
  attn_k<<<2048, 256, 0, stream>>>(Qb, Kb, Vt, pb, gate, AO);
  gemm_out_k<<<dim3(16, 8), 256, 0, stream>>>(AO, woutb, bout, (float*)d_out);
}